// Round 1
// baseline (341.790 us; speedup 1.0000x reference)
//
#include <hip/hip_runtime.h>
#include <cstdint>
#include <cstddef>

// Problem constants (B=32, D=256, H=32, W=32, K=1024)
// N = B*H*W = 32768 points. z_e layout: [b][d][h][w] -> point n=(b,hw) reads stride-1024.
#define NPTS   32768
#define DIM    256
#define KCODES 1024

// ---------------------------------------------------------------------------
// kernel 0a: transpose codebook [1024][256] -> ctT [256][1024] (d-major)
// ---------------------------------------------------------------------------
__global__ __launch_bounds__(256)
void vq_transpose_kernel(const float* __restrict__ cb, float* __restrict__ ctT)
{
    __shared__ float tile[64 * 65];
    const int t  = threadIdx.x;
    const int kb = blockIdx.x >> 2;   // 16 k-tiles of 64
    const int db = blockIdx.x & 3;    // 4  d-tiles of 64
    const int k0 = kb << 6, d0 = db << 6;
#pragma unroll
    for (int i = 0; i < 16; ++i) {
        int idx = i * 256 + t;
        int r = idx >> 6, c = idx & 63;            // r: k-row, c: d-col
        tile[r * 65 + c] = cb[(size_t)(k0 + r) * 256 + d0 + c];
    }
    __syncthreads();
#pragma unroll
    for (int i = 0; i < 16; ++i) {
        int idx = i * 256 + t;
        int r = idx >> 6, c = idx & 63;            // r: d-row, c: k-col
        ctT[(size_t)(d0 + r) * 1024 + k0 + c] = tile[c * 65 + r];
    }
}

// ---------------------------------------------------------------------------
// kernel 0b: codebook row norms ||c_k||^2
// ---------------------------------------------------------------------------
__global__ __launch_bounds__(256)
void vq_cnorm_kernel(const float* __restrict__ cb, float* __restrict__ cnorm)
{
    const int k = blockIdx.x * 256 + threadIdx.x;  // grid=4
    const float4* row = reinterpret_cast<const float4*>(cb + (size_t)k * 256);
    float s0 = 0.f, s1 = 0.f, s2 = 0.f, s3 = 0.f;
#pragma unroll 8
    for (int i = 0; i < 64; ++i) {
        float4 v = row[i];
        s0 = fmaf(v.x, v.x, s0);
        s1 = fmaf(v.y, v.y, s1);
        s2 = fmaf(v.z, v.z, s2);
        s3 = fmaf(v.w, v.w, s3);
    }
    cnorm[k] = (s0 + s1) + (s2 + s3);
}

// ---------------------------------------------------------------------------
// kernel 1: argmin over codes.
// Block: 256 threads = 8 ty * 32 tx. Tile: 64 points x 256 codes per kt.
// Per-thread register tile: 8 points x 8 codes (64 fp32 accs).
// LDS: zt[256][64] = 64KB (resident), ct[16][256] = 16KB (streamed) -> 80KB.
// dist = ||c||^2 - 2*dot  (z^2 is constant per point, drops out of argmin).
// ---------------------------------------------------------------------------
__global__ __launch_bounds__(256, 2)
void vq_argmin_kernel(const float* __restrict__ z, const float* __restrict__ ctT,
                      const float* __restrict__ cnorm, int* __restrict__ codes,
                      float* __restrict__ out_idx)
{
    __shared__ float zt[256 * 64];   // [d][point]
    __shared__ float ct[16 * 256];   // [d][code]

    const int t   = threadIdx.x;
    const int tx  = t & 31;          // code groups
    const int ty  = t >> 5;          // 0..7, point groups
    const int p0  = ty << 3;         // 8 points per thread
    const int blk = blockIdx.x;      // 512 blocks x 64 points
    const int b   = blk >> 4;        // 16 blocks per image (1024 hw / 64)
    const int hw0 = (blk & 15) << 6;
    const float* zbase = z + ((size_t)b << 18) + hw0;   // z[b][d][hw0..]

    // stage zt[256][64]: coalesced float4 along hw
#pragma unroll
    for (int i = 0; i < 16; ++i) {
        int idx = i * 256 + t;
        int d = idx >> 4, c4 = (idx & 15) << 2;
        float4 v = *reinterpret_cast<const float4*>(zbase + (size_t)d * 1024 + c4);
        *reinterpret_cast<float4*>(&zt[d * 64 + c4]) = v;
    }

    float minv[8];
    int   mini[8];
#pragma unroll
    for (int i = 0; i < 8; ++i) { minv[i] = 3.0e38f; mini[i] = 0; }

    for (int kt = 0; kt < 4; ++kt) {            // 4 tiles of 256 codes
        const int k0 = kt << 8;
        float acc[8][8];
#pragma unroll
        for (int i = 0; i < 8; ++i)
#pragma unroll
            for (int j = 0; j < 8; ++j) acc[i][j] = 0.f;

        for (int dc = 0; dc < 16; ++dc) {       // 16 chunks of 16 d-rows
            const int d0 = dc << 4;
            __syncthreads();                    // previous ct fully consumed (also covers zt staging)
#pragma unroll
            for (int i = 0; i < 4; ++i) {       // stage ct[16][256] = 16KB
                int idx = i * 256 + t;
                int r = idx >> 6, c4 = (idx & 63) << 2;
                float4 v = *reinterpret_cast<const float4*>(ctT + (size_t)(d0 + r) * 1024 + k0 + c4);
                *reinterpret_cast<float4*>(&ct[r * 256 + c4]) = v;
            }
            __syncthreads();

#pragma unroll 2
            for (int d = 0; d < 16; ++d) {
                const float* zr = &zt[(d0 + d) * 64 + p0];
                float4 za = *reinterpret_cast<const float4*>(zr);
                float4 zb = *reinterpret_cast<const float4*>(zr + 4);
                const float* cr = &ct[d * 256 + (tx << 2)];
                float4 ca  = *reinterpret_cast<const float4*>(cr);
                float4 cb2 = *reinterpret_cast<const float4*>(cr + 128);
                float zz[8] = { za.x, za.y, za.z, za.w, zb.x, zb.y, zb.z, zb.w };
                float cc[8] = { ca.x, ca.y, ca.z, ca.w, cb2.x, cb2.y, cb2.z, cb2.w };
#pragma unroll
                for (int i = 0; i < 8; ++i)
#pragma unroll
                    for (int j = 0; j < 8; ++j)
                        acc[i][j] = fmaf(zz[i], cc[j], acc[i][j]);
            }
        }

        // epilogue: distances + running min (ascending k per thread -> first-index ties)
#pragma unroll
        for (int j = 0; j < 8; ++j) {
            const int k = k0 + ((j < 4) ? ((tx << 2) + j) : (128 + (tx << 2) + (j - 4)));
            const float cn = cnorm[k];
#pragma unroll
            for (int i = 0; i < 8; ++i) {
                float dist = fmaf(-2.0f, acc[i][j], cn);
                if (dist < minv[i]) { minv[i] = dist; mini[i] = k; }
            }
        }
    }

    // reduce across the 32 tx lanes (point rows live in matching lanes)
#pragma unroll
    for (int m = 1; m <= 16; m <<= 1) {
#pragma unroll
        for (int i = 0; i < 8; ++i) {
            float ov = __shfl_xor(minv[i], m, 64);
            int   oi = __shfl_xor(mini[i], m, 64);
            if (ov < minv[i] || (ov == minv[i] && oi < mini[i])) { minv[i] = ov; mini[i] = oi; }
        }
    }
    if (tx == 0) {
        const int n0 = (blk << 6) + p0;
#pragma unroll
        for (int i = 0; i < 8; ++i) {
            codes[n0 + i]   = mini[i];
            out_idx[n0 + i] = (float)mini[i];
        }
    }
}

// ---------------------------------------------------------------------------
// kernel 2: gather z_q, write output 0 (coalesced), accumulate vq_loss.
// Block: 64 points (one hw-stripe), stages the 64 selected codebook rows in
// LDS with pad 257 (read-phase banks (hw+d)%32 -> 2-way = free).
// ---------------------------------------------------------------------------
__global__ __launch_bounds__(256, 2)
void vq_gather_kernel(const float* __restrict__ cb, const float* __restrict__ z,
                      const int* __restrict__ codes, float* __restrict__ out_zq,
                      float* __restrict__ loss)
{
    __shared__ float rows[64 * 257];
    __shared__ int   ks[64];
    __shared__ float wsum[4];

    const int t   = threadIdx.x;
    const int blk = blockIdx.x;            // 512 blocks
    const int b   = blk >> 4;
    const int hw0 = (blk & 15) << 6;
    const int n0  = blk << 6;

    if (t < 64) ks[t] = codes[n0 + t];
    __syncthreads();

#pragma unroll 4
    for (int i = 0; i < 64; ++i) {         // stage 64 rows x 256 floats, coalesced
        rows[i * 257 + t] = cb[(size_t)ks[i] * 256 + t];
    }
    __syncthreads();

    const int dq = t >> 6;                 // 0..3 (d quadrant)
    const int hw = t & 63;
    const size_t obase = ((size_t)b << 18) + hw0 + hw;
    float sum = 0.f;
#pragma unroll 4
    for (int dd = 0; dd < 64; ++dd) {
        const int d = (dq << 6) + dd;
        const float  q  = rows[hw * 257 + d];
        const size_t a  = obase + (size_t)d * 1024;
        const float  zv = z[a];
        out_zq[a] = q;
        const float diff = q - zv;
        sum = fmaf(diff, diff, sum);
    }

    // wave reduce (width 64) then block reduce
#pragma unroll
    for (int m = 1; m <= 32; m <<= 1) sum += __shfl_xor(sum, m, 64);
    if ((t & 63) == 0) wsum[t >> 6] = sum;
    __syncthreads();
    if (t == 0) {
        const float s = (wsum[0] + wsum[1]) + (wsum[2] + wsum[3]);
        // vq_loss = (1 + 0.25) * SSE / (B*D*H*W)
        atomicAdd(loss, s * (1.25f / 8388608.0f));
    }
}

// ---------------------------------------------------------------------------
extern "C" void kernel_launch(void* const* d_in, const int* in_sizes, int n_in,
                              void* d_out, int out_size, void* d_ws, size_t ws_size,
                              hipStream_t stream)
{
    (void)in_sizes; (void)n_in; (void)out_size; (void)ws_size;

    const float* z  = (const float*)d_in[0];   // 32*256*32*32 fp32
    const float* cb = (const float*)d_in[1];   // 1024*256 fp32

    float* out      = (float*)d_out;
    float* out_zq   = out;                     // 8388608
    float* out_idx  = out + 8388608;           // 32768 (indices as float values)
    float* out_loss = out + 8421376;           // 1

    float* ctT   = (float*)d_ws;               // 256*1024 fp32 = 1MB
    float* cnorm = ctT + 256 * 1024;           // 1024 fp32
    int*   codes = (int*)(cnorm + 1024);       // 32768 int32

    hipMemsetAsync(out_loss, 0, sizeof(float), stream);
    vq_transpose_kernel<<<64, 256, 0, stream>>>(cb, ctT);
    vq_cnorm_kernel<<<4, 256, 0, stream>>>(cb, cnorm);
    vq_argmin_kernel<<<512, 256, 0, stream>>>(z, ctT, cnorm, codes, out_idx);
    vq_gather_kernel<<<512, 256, 0, stream>>>(cb, z, codes, out_zq, out_loss);
}

// Round 2
// 304.413 us; speedup vs baseline: 1.1228x; 1.1228x over previous
//
#include <hip/hip_runtime.h>
#include <cstdint>
#include <cstddef>

// Problem constants (B=32, D=256, H=32, W=32, K=1024)
// N = B*H*W = 32768 points. z_e layout: [b][d][h][w] -> point n=(b,hw) reads stride-1024.
#define NPTS   32768
#define DIM    256
#define KCODES 1024

// ---------------------------------------------------------------------------
// kernel 0a: transpose codebook [1024][256] -> ctT [256][1024] (d-major)
// ---------------------------------------------------------------------------
__global__ __launch_bounds__(256)
void vq_transpose_kernel(const float* __restrict__ cb, float* __restrict__ ctT)
{
    __shared__ float tile[64 * 65];
    const int t  = threadIdx.x;
    const int kb = blockIdx.x >> 2;   // 16 k-tiles of 64
    const int db = blockIdx.x & 3;    // 4  d-tiles of 64
    const int k0 = kb << 6, d0 = db << 6;
#pragma unroll
    for (int i = 0; i < 16; ++i) {
        int idx = i * 256 + t;
        int r = idx >> 6, c = idx & 63;            // r: k-row, c: d-col
        tile[r * 65 + c] = cb[(size_t)(k0 + r) * 256 + d0 + c];
    }
    __syncthreads();
#pragma unroll
    for (int i = 0; i < 16; ++i) {
        int idx = i * 256 + t;
        int r = idx >> 6, c = idx & 63;            // r: d-row, c: k-col
        ctT[(size_t)(d0 + r) * 1024 + k0 + c] = tile[c * 65 + r];
    }
}

// ---------------------------------------------------------------------------
// kernel 0b: codebook row norms ||c_k||^2
// ---------------------------------------------------------------------------
__global__ __launch_bounds__(256)
void vq_cnorm_kernel(const float* __restrict__ cb, float* __restrict__ cnorm)
{
    const int k = blockIdx.x * 256 + threadIdx.x;  // grid=4
    const float4* row = reinterpret_cast<const float4*>(cb + (size_t)k * 256);
    float s0 = 0.f, s1 = 0.f, s2 = 0.f, s3 = 0.f;
#pragma unroll 8
    for (int i = 0; i < 64; ++i) {
        float4 v = row[i];
        s0 = fmaf(v.x, v.x, s0);
        s1 = fmaf(v.y, v.y, s1);
        s2 = fmaf(v.z, v.z, s2);
        s3 = fmaf(v.w, v.w, s3);
    }
    cnorm[k] = (s0 + s1) + (s2 + s3);
}

// ---------------------------------------------------------------------------
// kernel 1: argmin over codes.
// Block: 512 threads = 8 ty (point groups) * 64 tx (code lanes).
// Tile: 64 points x 256 codes per kt. Per-thread: 8 points x 4 codes.
// LDS: zt[256][64] = 64KB (resident), ct[16][256] = 16KB (streamed) -> 80KB.
// 2 blocks/CU = 16 waves/CU = 4 waves/SIMD.
// dist = ||c||^2 - 2*dot  (z^2 is constant per point, drops out of argmin).
// Inner loop: 3 ds_read_b128 (2 broadcast z + 1 linear c) + 32 v_fmac per d,
// all offsets compile-time immediates (full unroll).
// ---------------------------------------------------------------------------
__global__ __launch_bounds__(512, 4)
void vq_argmin_kernel(const float* __restrict__ z, const float* __restrict__ ctT,
                      const float* __restrict__ cnorm, int* __restrict__ codes,
                      float* __restrict__ out_idx)
{
    __shared__ float zt[256 * 64];   // [d][point]
    __shared__ float ct[16 * 256];   // [d][code]

    const int t   = threadIdx.x;
    const int tx  = t & 63;          // code lane: codes tx*4 .. tx*4+3
    const int ty  = t >> 6;          // 0..7, point group: points ty*8 .. ty*8+7
    const int p0  = ty << 3;
    const int blk = blockIdx.x;      // 512 blocks x 64 points
    const int b   = blk >> 4;        // 16 blocks per image (1024 hw / 64)
    const int hw0 = (blk & 15) << 6;
    const float* zbase = z + ((size_t)b << 18) + hw0;   // z[b][d][hw0..]

    // stage zt[256][64]: 8 float4/thread, LDS-linear (conflict-free), coalesced global
#pragma unroll
    for (int i = 0; i < 8; ++i) {
        int idx = i * 512 + t;
        int d = idx >> 4, c4 = (idx & 15) << 2;
        float4 v = *reinterpret_cast<const float4*>(zbase + (size_t)d * 1024 + c4);
        *reinterpret_cast<float4*>(&zt[d * 64 + c4]) = v;
    }

    float minv[8];
    int   mini[8];
#pragma unroll
    for (int i = 0; i < 8; ++i) { minv[i] = 3.0e38f; mini[i] = 0; }

    const float* zrd = &zt[p0];          // + d*64 per row
    const float* crd = &ct[tx << 2];     // + d*256 per row

    for (int kt = 0; kt < 4; ++kt) {            // 4 tiles of 256 codes
        const int k0 = kt << 8;
        float acc[8][4];
#pragma unroll
        for (int i = 0; i < 8; ++i)
#pragma unroll
            for (int j = 0; j < 4; ++j) acc[i][j] = 0.f;

        for (int dc = 0; dc < 16; ++dc) {       // 16 chunks of 16 d-rows
            const int d0 = dc << 4;
            __syncthreads();                    // previous ct fully consumed (covers zt staging too)
#pragma unroll
            for (int i = 0; i < 2; ++i) {       // stage ct[16][256] = 16KB, LDS-linear
                int idx = i * 512 + t;
                int r = idx >> 6, c4 = (idx & 63) << 2;
                float4 v = *reinterpret_cast<const float4*>(ctT + (size_t)(d0 + r) * 1024 + k0 + c4);
                *reinterpret_cast<float4*>(&ct[r * 256 + c4]) = v;
            }
            __syncthreads();

            const float* zp = zrd + d0 * 64;
#pragma unroll
            for (int d = 0; d < 16; ++d) {
                float4 za = *reinterpret_cast<const float4*>(zp + d * 64);      // broadcast
                float4 zb = *reinterpret_cast<const float4*>(zp + d * 64 + 4);  // broadcast
                float4 cc = *reinterpret_cast<const float4*>(crd + d * 256);    // linear
#define VQ_FMA_ROW(ii, zv)                          \
                acc[ii][0] = fmaf(zv, cc.x, acc[ii][0]); \
                acc[ii][1] = fmaf(zv, cc.y, acc[ii][1]); \
                acc[ii][2] = fmaf(zv, cc.z, acc[ii][2]); \
                acc[ii][3] = fmaf(zv, cc.w, acc[ii][3]);
                VQ_FMA_ROW(0, za.x)
                VQ_FMA_ROW(1, za.y)
                VQ_FMA_ROW(2, za.z)
                VQ_FMA_ROW(3, za.w)
                VQ_FMA_ROW(4, zb.x)
                VQ_FMA_ROW(5, zb.y)
                VQ_FMA_ROW(6, zb.z)
                VQ_FMA_ROW(7, zb.w)
#undef VQ_FMA_ROW
            }
        }

        // epilogue: distances + running min (ascending k per thread -> first-index ties)
#pragma unroll
        for (int j = 0; j < 4; ++j) {
            const int k = k0 + (tx << 2) + j;
            const float cn = cnorm[k];
#pragma unroll
            for (int i = 0; i < 8; ++i) {
                float dist = fmaf(-2.0f, acc[i][j], cn);
                if (dist < minv[i]) { minv[i] = dist; mini[i] = k; }
            }
        }
    }

    // reduce across the 64 tx lanes of the wave (lexicographic (v, k) min)
#pragma unroll
    for (int m = 1; m <= 32; m <<= 1) {
#pragma unroll
        for (int i = 0; i < 8; ++i) {
            float ov = __shfl_xor(minv[i], m, 64);
            int   oi = __shfl_xor(mini[i], m, 64);
            if (ov < minv[i] || (ov == minv[i] && oi < mini[i])) { minv[i] = ov; mini[i] = oi; }
        }
    }
    if (tx == 0) {
        const int n0 = (blk << 6) + p0;
#pragma unroll
        for (int i = 0; i < 8; ++i) {
            codes[n0 + i]   = mini[i];
            out_idx[n0 + i] = (float)mini[i];
        }
    }
}

// ---------------------------------------------------------------------------
// kernel 2: gather z_q, write output 0 (coalesced), accumulate vq_loss.
// Block: 64 points (one hw-stripe), stages the 64 selected codebook rows in
// LDS with pad 257 (read-phase banks (hw+d)%32 -> conflict-free).
// ---------------------------------------------------------------------------
__global__ __launch_bounds__(256, 2)
void vq_gather_kernel(const float* __restrict__ cb, const float* __restrict__ z,
                      const int* __restrict__ codes, float* __restrict__ out_zq,
                      float* __restrict__ loss)
{
    __shared__ float rows[64 * 257];
    __shared__ int   ks[64];
    __shared__ float wsum[4];

    const int t   = threadIdx.x;
    const int blk = blockIdx.x;            // 512 blocks
    const int b   = blk >> 4;
    const int hw0 = (blk & 15) << 6;
    const int n0  = blk << 6;

    if (t < 64) ks[t] = codes[n0 + t];
    __syncthreads();

#pragma unroll 4
    for (int i = 0; i < 64; ++i) {         // stage 64 rows x 256 floats, coalesced
        rows[i * 257 + t] = cb[(size_t)ks[i] * 256 + t];
    }
    __syncthreads();

    const int dq = t >> 6;                 // 0..3 (d quadrant)
    const int hw = t & 63;
    const size_t obase = ((size_t)b << 18) + hw0 + hw;
    float sum = 0.f;
#pragma unroll 4
    for (int dd = 0; dd < 64; ++dd) {
        const int d = (dq << 6) + dd;
        const float  q  = rows[hw * 257 + d];
        const size_t a  = obase + (size_t)d * 1024;
        const float  zv = z[a];
        out_zq[a] = q;
        const float diff = q - zv;
        sum = fmaf(diff, diff, sum);
    }

    // wave reduce (width 64) then block reduce
#pragma unroll
    for (int m = 1; m <= 32; m <<= 1) sum += __shfl_xor(sum, m, 64);
    if ((t & 63) == 0) wsum[t >> 6] = sum;
    __syncthreads();
    if (t == 0) {
        const float s = (wsum[0] + wsum[1]) + (wsum[2] + wsum[3]);
        // vq_loss = (1 + 0.25) * SSE / (B*D*H*W)
        atomicAdd(loss, s * (1.25f / 8388608.0f));
    }
}

// ---------------------------------------------------------------------------
extern "C" void kernel_launch(void* const* d_in, const int* in_sizes, int n_in,
                              void* d_out, int out_size, void* d_ws, size_t ws_size,
                              hipStream_t stream)
{
    (void)in_sizes; (void)n_in; (void)out_size; (void)ws_size;

    const float* z  = (const float*)d_in[0];   // 32*256*32*32 fp32
    const float* cb = (const float*)d_in[1];   // 1024*256 fp32

    float* out      = (float*)d_out;
    float* out_zq   = out;                     // 8388608
    float* out_idx  = out + 8388608;           // 32768 (indices as float values)
    float* out_loss = out + 8421376;           // 1

    float* ctT   = (float*)d_ws;               // 256*1024 fp32 = 1MB
    float* cnorm = ctT + 256 * 1024;           // 1024 fp32
    int*   codes = (int*)(cnorm + 1024);       // 32768 int32

    hipMemsetAsync(out_loss, 0, sizeof(float), stream);
    vq_transpose_kernel<<<64, 256, 0, stream>>>(cb, ctT);
    vq_cnorm_kernel<<<4, 256, 0, stream>>>(cb, cnorm);
    vq_argmin_kernel<<<512, 512, 0, stream>>>(z, ctT, cnorm, codes, out_idx);
    vq_gather_kernel<<<512, 256, 0, stream>>>(cb, z, codes, out_zq, out_loss);
}

// Round 3
// 272.449 us; speedup vs baseline: 1.2545x; 1.1173x over previous
//
#include <hip/hip_runtime.h>
#include <cstdint>
#include <cstddef>

// Problem constants (B=32, D=256, H=32, W=32, K=1024)
// N = B*H*W = 32768 points. z_e layout: [b][d][h][w] -> point n=(b,hw) reads stride-1024.
#define NPTS   32768
#define DIM    256
#define KCODES 1024

// ---------------------------------------------------------------------------
// kernel 0a: transpose codebook [1024][256] -> ctT [256][1024] (d-major)
// ---------------------------------------------------------------------------
__global__ __launch_bounds__(256)
void vq_transpose_kernel(const float* __restrict__ cb, float* __restrict__ ctT)
{
    __shared__ float tile[64 * 65];
    const int t  = threadIdx.x;
    const int kb = blockIdx.x >> 2;   // 16 k-tiles of 64
    const int db = blockIdx.x & 3;    // 4  d-tiles of 64
    const int k0 = kb << 6, d0 = db << 6;
#pragma unroll
    for (int i = 0; i < 16; ++i) {
        int idx = i * 256 + t;
        int r = idx >> 6, c = idx & 63;            // r: k-row, c: d-col
        tile[r * 65 + c] = cb[(size_t)(k0 + r) * 256 + d0 + c];
    }
    __syncthreads();
#pragma unroll
    for (int i = 0; i < 16; ++i) {
        int idx = i * 256 + t;
        int r = idx >> 6, c = idx & 63;            // r: d-row, c: k-col
        ctT[(size_t)(d0 + r) * 1024 + k0 + c] = tile[c * 65 + r];
    }
}

// ---------------------------------------------------------------------------
// kernel 0b: codebook row norms ||c_k||^2
// ---------------------------------------------------------------------------
__global__ __launch_bounds__(256)
void vq_cnorm_kernel(const float* __restrict__ cb, float* __restrict__ cnorm)
{
    const int k = blockIdx.x * 256 + threadIdx.x;  // grid=4
    const float4* row = reinterpret_cast<const float4*>(cb + (size_t)k * 256);
    float s0 = 0.f, s1 = 0.f, s2 = 0.f, s3 = 0.f;
#pragma unroll 8
    for (int i = 0; i < 64; ++i) {
        float4 v = row[i];
        s0 = fmaf(v.x, v.x, s0);
        s1 = fmaf(v.y, v.y, s1);
        s2 = fmaf(v.z, v.z, s2);
        s3 = fmaf(v.w, v.w, s3);
    }
    cnorm[k] = (s0 + s1) + (s2 + s3);
}

// ---------------------------------------------------------------------------
// kernel 1: argmin over codes.
// Block: 512 threads = 8 ty (point groups) * 64 tx (code lanes).
// Tile: 64 points x 256 codes per kt. Per-thread: 8 points x 4 codes.
// LDS: zt[256][64] = 64KB (resident), ct[16][256] = 16KB (streamed) -> 80KB.
// LDS limits to 2 blocks/CU = 16 waves/CU = 4 waves/SIMD.
// __launch_bounds__(512,2): VGPR cap >= 128 (kernel needs ~90).
//   (512,4) capped VGPRs at 64 -> acc[8][4] spilled to scratch: WRITE_SIZE
//   ballooned to 314MB and VALUBusy fell to 50%. Do not lower this bound.
// dist = ||c||^2 - 2*dot  (z^2 is constant per point, drops out of argmin).
// Inner loop: 3 ds_read_b128 (2 broadcast z + 1 linear c) + 32 v_fmac per d,
// all offsets compile-time immediates (full unroll).
// ---------------------------------------------------------------------------
__global__ __launch_bounds__(512, 2)
void vq_argmin_kernel(const float* __restrict__ z, const float* __restrict__ ctT,
                      const float* __restrict__ cnorm, int* __restrict__ codes,
                      float* __restrict__ out_idx)
{
    __shared__ float zt[256 * 64];   // [d][point]
    __shared__ float ct[16 * 256];   // [d][code]

    const int t   = threadIdx.x;
    const int tx  = t & 63;          // code lane: codes tx*4 .. tx*4+3
    const int ty  = t >> 6;          // 0..7, point group: points ty*8 .. ty*8+7
    const int p0  = ty << 3;
    const int blk = blockIdx.x;      // 512 blocks x 64 points
    const int b   = blk >> 4;        // 16 blocks per image (1024 hw / 64)
    const int hw0 = (blk & 15) << 6;
    const float* zbase = z + ((size_t)b << 18) + hw0;   // z[b][d][hw0..]

    // stage zt[256][64]: 8 float4/thread, LDS-linear (conflict-free), coalesced global
#pragma unroll
    for (int i = 0; i < 8; ++i) {
        int idx = i * 512 + t;
        int d = idx >> 4, c4 = (idx & 15) << 2;
        float4 v = *reinterpret_cast<const float4*>(zbase + (size_t)d * 1024 + c4);
        *reinterpret_cast<float4*>(&zt[d * 64 + c4]) = v;
    }

    float minv[8];
    int   mini[8];
#pragma unroll
    for (int i = 0; i < 8; ++i) { minv[i] = 3.0e38f; mini[i] = 0; }

    const float* zrd = &zt[p0];          // + d*64 per row
    const float* crd = &ct[tx << 2];     // + d*256 per row

    for (int kt = 0; kt < 4; ++kt) {            // 4 tiles of 256 codes
        const int k0 = kt << 8;
        float acc[8][4];
#pragma unroll
        for (int i = 0; i < 8; ++i)
#pragma unroll
            for (int j = 0; j < 4; ++j) acc[i][j] = 0.f;

        for (int dc = 0; dc < 16; ++dc) {       // 16 chunks of 16 d-rows
            const int d0 = dc << 4;
            __syncthreads();                    // previous ct fully consumed (covers zt staging too)
#pragma unroll
            for (int i = 0; i < 2; ++i) {       // stage ct[16][256] = 16KB, LDS-linear
                int idx = i * 512 + t;
                int r = idx >> 6, c4 = (idx & 63) << 2;
                float4 v = *reinterpret_cast<const float4*>(ctT + (size_t)(d0 + r) * 1024 + k0 + c4);
                *reinterpret_cast<float4*>(&ct[r * 256 + c4]) = v;
            }
            __syncthreads();

            const float* zp = zrd + d0 * 64;
#pragma unroll
            for (int d = 0; d < 16; ++d) {
                float4 za = *reinterpret_cast<const float4*>(zp + d * 64);      // broadcast
                float4 zb = *reinterpret_cast<const float4*>(zp + d * 64 + 4);  // broadcast
                float4 cc = *reinterpret_cast<const float4*>(crd + d * 256);    // linear
#define VQ_FMA_ROW(ii, zv)                          \
                acc[ii][0] = fmaf(zv, cc.x, acc[ii][0]); \
                acc[ii][1] = fmaf(zv, cc.y, acc[ii][1]); \
                acc[ii][2] = fmaf(zv, cc.z, acc[ii][2]); \
                acc[ii][3] = fmaf(zv, cc.w, acc[ii][3]);
                VQ_FMA_ROW(0, za.x)
                VQ_FMA_ROW(1, za.y)
                VQ_FMA_ROW(2, za.z)
                VQ_FMA_ROW(3, za.w)
                VQ_FMA_ROW(4, zb.x)
                VQ_FMA_ROW(5, zb.y)
                VQ_FMA_ROW(6, zb.z)
                VQ_FMA_ROW(7, zb.w)
#undef VQ_FMA_ROW
            }
        }

        // epilogue: distances + running min (ascending k per thread -> first-index ties)
#pragma unroll
        for (int j = 0; j < 4; ++j) {
            const int k = k0 + (tx << 2) + j;
            const float cn = cnorm[k];
#pragma unroll
            for (int i = 0; i < 8; ++i) {
                float dist = fmaf(-2.0f, acc[i][j], cn);
                if (dist < minv[i]) { minv[i] = dist; mini[i] = k; }
            }
        }
    }

    // reduce across the 64 tx lanes of the wave (lexicographic (v, k) min)
#pragma unroll
    for (int m = 1; m <= 32; m <<= 1) {
#pragma unroll
        for (int i = 0; i < 8; ++i) {
            float ov = __shfl_xor(minv[i], m, 64);
            int   oi = __shfl_xor(mini[i], m, 64);
            if (ov < minv[i] || (ov == minv[i] && oi < mini[i])) { minv[i] = ov; mini[i] = oi; }
        }
    }
    if (tx == 0) {
        const int n0 = (blk << 6) + p0;
#pragma unroll
        for (int i = 0; i < 8; ++i) {
            codes[n0 + i]   = mini[i];
            out_idx[n0 + i] = (float)mini[i];
        }
    }
}

// ---------------------------------------------------------------------------
// kernel 2: gather z_q, write output 0 (coalesced), accumulate vq_loss.
// Block: 64 points (one hw-stripe), stages the 64 selected codebook rows in
// LDS with pad 257 (read-phase banks (hw+d)%32 -> conflict-free).
// ---------------------------------------------------------------------------
__global__ __launch_bounds__(256, 2)
void vq_gather_kernel(const float* __restrict__ cb, const float* __restrict__ z,
                      const int* __restrict__ codes, float* __restrict__ out_zq,
                      float* __restrict__ loss)
{
    __shared__ float rows[64 * 257];
    __shared__ int   ks[64];
    __shared__ float wsum[4];

    const int t   = threadIdx.x;
    const int blk = blockIdx.x;            // 512 blocks
    const int b   = blk >> 4;
    const int hw0 = (blk & 15) << 6;
    const int n0  = blk << 6;

    if (t < 64) ks[t] = codes[n0 + t];
    __syncthreads();

#pragma unroll 4
    for (int i = 0; i < 64; ++i) {         // stage 64 rows x 256 floats, coalesced
        rows[i * 257 + t] = cb[(size_t)ks[i] * 256 + t];
    }
    __syncthreads();

    const int dq = t >> 6;                 // 0..3 (d quadrant)
    const int hw = t & 63;
    const size_t obase = ((size_t)b << 18) + hw0 + hw;
    float sum = 0.f;
#pragma unroll 4
    for (int dd = 0; dd < 64; ++dd) {
        const int d = (dq << 6) + dd;
        const float  q  = rows[hw * 257 + d];
        const size_t a  = obase + (size_t)d * 1024;
        const float  zv = z[a];
        out_zq[a] = q;
        const float diff = q - zv;
        sum = fmaf(diff, diff, sum);
    }

    // wave reduce (width 64) then block reduce
#pragma unroll
    for (int m = 1; m <= 32; m <<= 1) sum += __shfl_xor(sum, m, 64);
    if ((t & 63) == 0) wsum[t >> 6] = sum;
    __syncthreads();
    if (t == 0) {
        const float s = (wsum[0] + wsum[1]) + (wsum[2] + wsum[3]);
        // vq_loss = (1 + 0.25) * SSE / (B*D*H*W)
        atomicAdd(loss, s * (1.25f / 8388608.0f));
    }
}

// ---------------------------------------------------------------------------
extern "C" void kernel_launch(void* const* d_in, const int* in_sizes, int n_in,
                              void* d_out, int out_size, void* d_ws, size_t ws_size,
                              hipStream_t stream)
{
    (void)in_sizes; (void)n_in; (void)out_size; (void)ws_size;

    const float* z  = (const float*)d_in[0];   // 32*256*32*32 fp32
    const float* cb = (const float*)d_in[1];   // 1024*256 fp32

    float* out      = (float*)d_out;
    float* out_zq   = out;                     // 8388608
    float* out_idx  = out + 8388608;           // 32768 (indices as float values)
    float* out_loss = out + 8421376;           // 1

    float* ctT   = (float*)d_ws;               // 256*1024 fp32 = 1MB
    float* cnorm = ctT + 256 * 1024;           // 1024 fp32
    int*   codes = (int*)(cnorm + 1024);       // 32768 int32

    hipMemsetAsync(out_loss, 0, sizeof(float), stream);
    vq_transpose_kernel<<<64, 256, 0, stream>>>(cb, ctT);
    vq_cnorm_kernel<<<4, 256, 0, stream>>>(cb, cnorm);
    vq_argmin_kernel<<<512, 512, 0, stream>>>(z, ctT, cnorm, codes, out_idx);
    vq_gather_kernel<<<512, 256, 0, stream>>>(cb, z, codes, out_zq, out_loss);
}